// Round 3
// baseline (263.631 us; speedup 1.0000x reference)
//
#include <hip/hip_runtime.h>

#define N_VOX 100000
#define K3 125
#define CENTER_K 62
#define CAP 4096
#define EPSF 1e-5f

// ws layout (float words):
#define WIT 0              // W_img lane-order [125][4][64][4]  (c = cs*16+t*4+e, lane = cs*16+o)
#define WPT 128000         // W_pts lane-order [125][2][64][4]  (c = cs*8+t*4+e)
#define WVT 192000         // W_vis lane-order [125][2][64][4]
#define CNT 256000         // counts, padded: k -> CNT + k*16 (2048 words)
#define PRS 258048         // pairs int2 [125][CAP] = 1,024,000 words
#define ACC 1282048        // accA [N][32] f32 (scatter accumulator, zeroed)
#define ACV 4482048        // accV [N][16] f32 (zeroed)
#define CAT 6082048        // cat [N][32] f32
// total 9,282,048 words = 37.1 MB

#define DOT4(a, w) ((a).x*(w).x + (a).y*(w).y + (a).z*(w).z + (a).w*(w).w)

// zero counts/acc/accV + transpose W into lane-order
__global__ __launch_bounds__(256) void prep(
    const float* __restrict__ Wi, const float* __restrict__ Wp,
    const float* __restrict__ Wv, float* __restrict__ ws)
{
    const int NZ = 2048 + 3200000 + 1600000;  // counts + accA + accV (contiguous from ACC)
    for (int i = blockIdx.x * 256 + threadIdx.x; i < NZ; i += gridDim.x * 256) {
        int a = (i < 2048) ? (CNT + i) : (ACC + i - 2048);
        ws[a] = 0.f;
        if (i < 128000) {  // Wi [k][c][o]: i = k*1024 + c*16 + o
            int k = i >> 10, r = i & 1023;
            int c = r >> 4, o = r & 15;
            int cs = c >> 4, t = (c >> 2) & 3, e = c & 3;
            ws[WIT + k * 1024 + t * 256 + (cs * 16 + o) * 4 + e] = Wi[i];
        }
        if (i < 64000) {
            int k = i / 512, r = i % 512;
            int c = r >> 4, o = r & 15;
            int cs = c >> 3, t = (c >> 2) & 1, e = c & 3;
            ws[WPT + k * 512 + t * 256 + (cs * 16 + o) * 4 + e] = Wp[i];
            ws[WVT + k * 512 + t * 256 + (cs * 16 + o) * 4 + e] = Wv[i];
        }
    }
}

// one pass over nbr -> per-k pair lists (skip always-valid center tap)
__global__ __launch_bounds__(256) void build_pairs(const int* __restrict__ nbr,
                                                   float* __restrict__ ws)
{
    int* cnt = (int*)(ws + CNT);
    int2* pairs = (int2*)(ws + PRS);
    const int TOT = N_VOX * K3;
    for (int i = blockIdx.x * 256 + threadIdx.x; i < TOT; i += gridDim.x * 256) {
        int idx = nbr[i];
        int k = i % K3;
        if (idx < N_VOX && k != CENTER_K) {
            int n = i / K3;
            int pos = atomicAdd(&cnt[k * 16], 1);
            if (pos < CAP) pairs[k * CAP + pos] = make_int2(n, idx);
        }
    }
}

// img+pts conv scatter: W[k] in LDS, pairs streamed with feature prefetch
__global__ __launch_bounds__(256) void scatterA(
    const float* __restrict__ fimg, const float* __restrict__ fpts,
    float* __restrict__ ws)
{
    int k = blockIdx.x;
    __shared__ float Wl[1536];
    {
        int tid = threadIdx.x;
        #pragma unroll
        for (int t = 0; t < 4; ++t) Wl[t * 256 + tid] = ws[WIT + k * 1024 + t * 256 + tid];
        #pragma unroll
        for (int t = 0; t < 2; ++t) Wl[1024 + t * 256 + tid] = ws[WPT + k * 512 + t * 256 + tid];
    }
    __syncthreads();
    int cnt = ((const int*)(ws + CNT))[k * 16];
    if (cnt > CAP) cnt = CAP;
    int chunk = (cnt + gridDim.y - 1) / gridDim.y;
    int start = blockIdx.y * chunk;
    int end = min(start + chunk, cnt);
    int wid = threadIdx.x >> 6, lane = threadIdx.x & 63;
    int cs = lane >> 4;
    const int2* __restrict__ pairs = (const int2*)(ws + PRS) + k * CAP;
    const float4* __restrict__ fi4 = (const float4*)fimg;
    const float4* __restrict__ fp4 = (const float4*)fpts;
    const float4* W4 = (const float4*)Wl;
    float* __restrict__ acc = ws + ACC;

    int p = start + wid;
    float4 A0, A1, A2, A3, P0, P1;
    int n = 0;
    if (p < end) {
        int2 pr = pairs[p]; n = pr.x;
        const float4* r = fi4 + pr.y * 16 + cs * 4;
        A0 = r[0]; A1 = r[1]; A2 = r[2]; A3 = r[3];
        const float4* q = fp4 + pr.y * 8 + cs * 2;
        P0 = q[0]; P1 = q[1];
    }
    while (p < end) {
        int pn = p + 4;
        int2 prn = make_int2(0, 0);
        if (pn < end) prn = pairs[pn];
        float4 w;
        float aI, aP;
        w = W4[lane];            aI  = DOT4(A0, w);
        w = W4[64 + lane];       aI += DOT4(A1, w);
        w = W4[128 + lane];      aI += DOT4(A2, w);
        w = W4[192 + lane];      aI += DOT4(A3, w);
        w = W4[256 + lane];      aP  = DOT4(P0, w);
        w = W4[320 + lane];      aP += DOT4(P1, w);
        int ncur = n;
        if (pn < end) {  // prefetch next pair's features while reduce/atomic retire
            n = prn.x;
            const float4* r = fi4 + prn.y * 16 + cs * 4;
            A0 = r[0]; A1 = r[1]; A2 = r[2]; A3 = r[3];
            const float4* q = fp4 + prn.y * 8 + cs * 2;
            P0 = q[0]; P1 = q[1];
        }
        aI += __shfl_xor(aI, 16); aI += __shfl_xor(aI, 32);
        aP += __shfl_xor(aP, 16); aP += __shfl_xor(aP, 32);
        if (lane < 32) atomicAdd(&acc[ncur * 32 + lane], lane < 16 ? aI : aP);
        p = pn;
    }
}

// center tap (j=n) + BN + ReLU -> cat
__global__ __launch_bounds__(256) void finalizeA(
    const float* __restrict__ fimg, const float* __restrict__ fpts,
    float* __restrict__ ws,
    const float* __restrict__ gi, const float* __restrict__ bi,
    const float* __restrict__ mi, const float* __restrict__ vi,
    const float* __restrict__ gp, const float* __restrict__ bp,
    const float* __restrict__ mp, const float* __restrict__ vp)
{
    int wid = threadIdx.x >> 6, lane = threadIdx.x & 63;
    int n = blockIdx.x * 4 + wid;
    if (n >= N_VOX) return;
    int o = lane & 15, cs = lane >> 4;
    const float4* fi4 = (const float4*)fimg + n * 16 + cs * 4;
    const float4* fp4 = (const float4*)fpts + n * 8 + cs * 2;
    const float4* wi4 = (const float4*)(ws + WIT + CENTER_K * 1024);
    const float4* wp4 = (const float4*)(ws + WPT + CENTER_K * 512);
    float aI = 0.f, aP = 0.f;
    #pragma unroll
    for (int t = 0; t < 4; ++t) { float4 f = fi4[t], w = wi4[t * 64 + lane]; aI += DOT4(f, w); }
    #pragma unroll
    for (int t = 0; t < 2; ++t) { float4 f = fp4[t], w = wp4[t * 64 + lane]; aP += DOT4(f, w); }
    aI += __shfl_xor(aI, 16); aI += __shfl_xor(aI, 32);
    aP += __shfl_xor(aP, 16); aP += __shfl_xor(aP, 32);
    if (lane < 32) {
        float tot = ws[ACC + n * 32 + lane] + (lane < 16 ? aI : aP);
        float g, b, m, v;
        if (lane < 16) { g = gi[o]; b = bi[o]; m = mi[o]; v = vi[o]; }
        else           { g = gp[o]; b = bp[o]; m = mp[o]; v = vp[o]; }
        float y = fmaxf((tot - m) * (g * rsqrtf(v + EPSF)) + b, 0.f);
        ws[CAT + n * 32 + lane] = y;
    }
}

// vis conv scatter on cat
__global__ __launch_bounds__(256) void scatterV(float* __restrict__ ws)
{
    int k = blockIdx.x;
    __shared__ float Wl[512];
    {
        int tid = threadIdx.x;
        #pragma unroll
        for (int t = 0; t < 2; ++t) Wl[t * 256 + tid] = ws[WVT + k * 512 + t * 256 + tid];
    }
    __syncthreads();
    int cnt = ((const int*)(ws + CNT))[k * 16];
    if (cnt > CAP) cnt = CAP;
    int chunk = (cnt + gridDim.y - 1) / gridDim.y;
    int start = blockIdx.y * chunk;
    int end = min(start + chunk, cnt);
    int wid = threadIdx.x >> 6, lane = threadIdx.x & 63;
    int cs = lane >> 4;
    const int2* __restrict__ pairs = (const int2*)(ws + PRS) + k * CAP;
    const float4* __restrict__ c4 = (const float4*)(ws + CAT);
    const float4* W4 = (const float4*)Wl;
    float* __restrict__ accV = ws + ACV;

    int p = start + wid;
    float4 C0, C1;
    int n = 0;
    if (p < end) {
        int2 pr = pairs[p]; n = pr.x;
        const float4* r = c4 + pr.y * 8 + cs * 2;
        C0 = r[0]; C1 = r[1];
    }
    while (p < end) {
        int pn = p + 4;
        int2 prn = make_int2(0, 0);
        if (pn < end) prn = pairs[pn];
        float4 w;
        float aV;
        w = W4[lane];       aV  = DOT4(C0, w);
        w = W4[64 + lane];  aV += DOT4(C1, w);
        int ncur = n;
        if (pn < end) {
            n = prn.x;
            const float4* r = c4 + prn.y * 8 + cs * 2;
            C0 = r[0]; C1 = r[1];
        }
        aV += __shfl_xor(aV, 16); aV += __shfl_xor(aV, 32);
        if (lane < 16) atomicAdd(&accV[ncur * 16 + lane], aV);
        p = pn;
    }
}

// vis center tap + BN + ReLU + sigmoid gate + blend -> out
__global__ __launch_bounds__(256) void finalizeB(
    float* __restrict__ ws,
    const float* __restrict__ gv, const float* __restrict__ bv,
    const float* __restrict__ mv, const float* __restrict__ vv,
    const float* __restrict__ w2, float* __restrict__ out)
{
    int wid = threadIdx.x >> 6, lane = threadIdx.x & 63;
    int n = blockIdx.x * 4 + wid;
    if (n >= N_VOX) return;
    int o = lane & 15, cs = lane >> 4;
    const float4* c4 = (const float4*)(ws + CAT) + n * 8 + cs * 2;
    const float4* wv4 = (const float4*)(ws + WVT + CENTER_K * 512);
    float aV = 0.f;
    #pragma unroll
    for (int t = 0; t < 2; ++t) { float4 f = c4[t], w = wv4[t * 64 + lane]; aV += DOT4(f, w); }
    aV += __shfl_xor(aV, 16); aV += __shfl_xor(aV, 32);
    // every lane now holds the full sum for o = lane & 15
    float sv = ws[ACV + n * 16 + o] + aV;
    float h = fmaxf((sv - mv[o]) * (gv[o] * rsqrtf(vv[o] + EPSF)) + bv[o], 0.f);
    float ph = h * w2[o];
    ph += __shfl_xor(ph, 1); ph += __shfl_xor(ph, 2);
    ph += __shfl_xor(ph, 4); ph += __shfl_xor(ph, 8);
    float vis = 1.f / (1.f + expf(-ph));
    if (lane < 16) {
        float xi = ws[CAT + n * 32 + o];
        float xp = ws[CAT + n * 32 + 16 + o];
        out[n * 16 + o] = vis * xi + (1.f - vis) * xp;
    }
}

extern "C" void kernel_launch(void* const* d_in, const int* in_sizes, int n_in,
                              void* d_out, int out_size, void* d_ws, size_t ws_size,
                              hipStream_t stream) {
    const float* fimg = (const float*)d_in[0];
    const float* fpts = (const float*)d_in[1];
    const int*   nbr  = (const int*)d_in[2];
    const float* Wimg = (const float*)d_in[3];
    const float* gi = (const float*)d_in[4];
    const float* bi = (const float*)d_in[5];
    const float* mi = (const float*)d_in[6];
    const float* vi = (const float*)d_in[7];
    const float* Wpts = (const float*)d_in[8];
    const float* gp = (const float*)d_in[9];
    const float* bp = (const float*)d_in[10];
    const float* mp = (const float*)d_in[11];
    const float* vp = (const float*)d_in[12];
    const float* Wvis = (const float*)d_in[13];
    const float* gv = (const float*)d_in[14];
    const float* bv = (const float*)d_in[15];
    const float* mv = (const float*)d_in[16];
    const float* vv = (const float*)d_in[17];
    const float* w2 = (const float*)d_in[18];
    float* out = (float*)d_out;
    float* ws = (float*)d_ws;

    hipLaunchKernelGGL(prep, dim3(2346), dim3(256), 0, stream, Wimg, Wpts, Wvis, ws);
    hipLaunchKernelGGL(build_pairs, dim3(6104), dim3(256), 0, stream, nbr, ws);
    hipLaunchKernelGGL(scatterA, dim3(125, 16), dim3(256), 0, stream, fimg, fpts, ws);
    hipLaunchKernelGGL(finalizeA, dim3(25000), dim3(256), 0, stream,
                       fimg, fpts, ws, gi, bi, mi, vi, gp, bp, mp, vp);
    hipLaunchKernelGGL(scatterV, dim3(125, 16), dim3(256), 0, stream, ws);
    hipLaunchKernelGGL(finalizeB, dim3(25000), dim3(256), 0, stream,
                       ws, gv, bv, mv, vv, w2, out);
}

// Round 4
// 202.236 us; speedup vs baseline: 1.3036x; 1.3036x over previous
//
#include <hip/hip_runtime.h>

#define N_VOX 100000
#define K3 125
#define CENTER_K 62
#define CAP 4096
#define EPSF 1e-5f

// ws layout (float-word offsets)
#define CNT 0                         // 125 counters padded x16 (2048 words)
#define PRS 2048                      // int2 pairs [125][CAP] = 1,024,000 words
#define ACC (2048 + 2 * 125 * CAP)    // accA [N][32]  (zeroed)
#define ACV (ACC + N_VOX * 32)        // accV [N][16]  (zeroed)
#define CAT (ACV + N_VOX * 16)        // cat  [N][32]
// end = 9,026,048 words = 36.1 MB

// zero counters + accA + accV (float4 stores)
__global__ __launch_bounds__(256) void prep(float* __restrict__ ws)
{
    float4 z = make_float4(0.f, 0.f, 0.f, 0.f);
    float4* w4 = (float4*)ws;
    const int NCNT4 = 2048 / 4;              // 512
    const int NACC4 = (N_VOX * 48) / 4;      // 1,200,000
    const int ACC4 = ACC / 4;
    for (int i = blockIdx.x * 256 + threadIdx.x; i < NCNT4 + NACC4; i += gridDim.x * 256)
        w4[i < NCNT4 ? i : ACC4 + (i - NCNT4)] = z;
}

// one pass over nbr -> per-k pair lists (center tap handled densely in finalize)
__global__ __launch_bounds__(256) void build_pairs(const int* __restrict__ nbr,
                                                   float* __restrict__ ws)
{
    int* cnt = (int*)(ws + CNT);
    int2* pairs = (int2*)(ws + PRS);
    const int TOT = N_VOX * K3;
    for (int i = blockIdx.x * 256 + threadIdx.x; i < TOT; i += gridDim.x * 256) {
        int idx = nbr[i];
        int k = i % K3;
        if (idx < N_VOX && k != CENTER_K) {
            int n = i / K3;
            int pos = atomicAdd(&cnt[k * 16], 1);
            if (pos < CAP) pairs[k * CAP + pos] = make_int2(n, idx);
        }
    }
}

// img+pts conv scatter: thread-per-(pair,o); W[k] column in VGPRs
__global__ __launch_bounds__(256) void scatterA(
    const float* __restrict__ fimg, const float* __restrict__ fpts,
    const float* __restrict__ Wimg, const float* __restrict__ Wpts,
    float* __restrict__ ws)
{
    int k = blockIdx.x;
    int o = threadIdx.x & 15;
    int slot = threadIdx.x >> 4;      // 0..15 pairs in flight per block
    float Wi_r[64];
    #pragma unroll
    for (int c = 0; c < 64; ++c) Wi_r[c] = Wimg[k * 1024 + c * 16 + o];
    float Wp_r[32];
    #pragma unroll
    for (int c = 0; c < 32; ++c) Wp_r[c] = Wpts[k * 512 + c * 16 + o];

    int cnt = ((const int*)(ws + CNT))[k * 16];
    if (cnt > CAP) cnt = CAP;
    const int2* __restrict__ pairs = (const int2*)(ws + PRS) + (size_t)k * CAP;
    float* __restrict__ acc = ws + ACC;
    const float4* __restrict__ fi4 = (const float4*)fimg;
    const float4* __restrict__ fp4 = (const float4*)fpts;

    for (int p = blockIdx.y * 16 + slot; p < cnt; p += gridDim.y * 16) {
        int2 pr = pairs[p];  // broadcast within laneset
        const float4* fr = fi4 + (size_t)pr.y * 16;
        const float4* gr = fp4 + (size_t)pr.y * 8;
        float aI = 0.f, aP = 0.f;
        #pragma unroll
        for (int t = 0; t < 16; ++t) {
            float4 f = fr[t];
            aI += f.x * Wi_r[4*t] + f.y * Wi_r[4*t+1] + f.z * Wi_r[4*t+2] + f.w * Wi_r[4*t+3];
        }
        #pragma unroll
        for (int t = 0; t < 8; ++t) {
            float4 f = gr[t];
            aP += f.x * Wp_r[4*t] + f.y * Wp_r[4*t+1] + f.z * Wp_r[4*t+2] + f.w * Wp_r[4*t+3];
        }
        atomicAdd(&acc[(size_t)pr.x * 32 + o], aI);
        atomicAdd(&acc[(size_t)pr.x * 32 + 16 + o], aP);
    }
}

// center tap + BN + ReLU -> cat; thread-per-(voxel,o), center W in VGPRs
__global__ __launch_bounds__(256) void finalizeA(
    const float* __restrict__ fimg, const float* __restrict__ fpts,
    const float* __restrict__ Wimg, const float* __restrict__ Wpts,
    float* __restrict__ ws,
    const float* __restrict__ gi, const float* __restrict__ bi,
    const float* __restrict__ mi, const float* __restrict__ vi,
    const float* __restrict__ gp, const float* __restrict__ bp,
    const float* __restrict__ mp, const float* __restrict__ vp)
{
    int o = threadIdx.x & 15;
    int slot = threadIdx.x >> 4;
    float Wi_r[64];
    #pragma unroll
    for (int c = 0; c < 64; ++c) Wi_r[c] = Wimg[CENTER_K * 1024 + c * 16 + o];
    float Wp_r[32];
    #pragma unroll
    for (int c = 0; c < 32; ++c) Wp_r[c] = Wpts[CENTER_K * 512 + c * 16 + o];
    float sI = gi[o] * rsqrtf(vi[o] + EPSF), bI = bi[o], mI = mi[o];
    float sP = gp[o] * rsqrtf(vp[o] + EPSF), bP = bp[o], mP = mp[o];

    const float4* __restrict__ fi4 = (const float4*)fimg;
    const float4* __restrict__ fp4 = (const float4*)fpts;
    const float* __restrict__ acc = ws + ACC;
    float* __restrict__ cat = ws + CAT;

    for (int n = blockIdx.x * 16 + slot; n < N_VOX; n += gridDim.x * 16) {
        const float4* fr = fi4 + (size_t)n * 16;
        const float4* gr = fp4 + (size_t)n * 8;
        float aI = 0.f, aP = 0.f;
        #pragma unroll
        for (int t = 0; t < 16; ++t) {
            float4 f = fr[t];
            aI += f.x * Wi_r[4*t] + f.y * Wi_r[4*t+1] + f.z * Wi_r[4*t+2] + f.w * Wi_r[4*t+3];
        }
        #pragma unroll
        for (int t = 0; t < 8; ++t) {
            float4 f = gr[t];
            aP += f.x * Wp_r[4*t] + f.y * Wp_r[4*t+1] + f.z * Wp_r[4*t+2] + f.w * Wp_r[4*t+3];
        }
        float tI = acc[(size_t)n * 32 + o] + aI;
        float tP = acc[(size_t)n * 32 + 16 + o] + aP;
        cat[(size_t)n * 32 + o]      = fmaxf((tI - mI) * sI + bI, 0.f);
        cat[(size_t)n * 32 + 16 + o] = fmaxf((tP - mP) * sP + bP, 0.f);
    }
}

// vis conv scatter on cat: thread-per-(pair,o)
__global__ __launch_bounds__(256) void scatterV(
    const float* __restrict__ Wvis, float* __restrict__ ws)
{
    int k = blockIdx.x;
    int o = threadIdx.x & 15;
    int slot = threadIdx.x >> 4;
    float Wv_r[32];
    #pragma unroll
    for (int c = 0; c < 32; ++c) Wv_r[c] = Wvis[k * 512 + c * 16 + o];

    int cnt = ((const int*)(ws + CNT))[k * 16];
    if (cnt > CAP) cnt = CAP;
    const int2* __restrict__ pairs = (const int2*)(ws + PRS) + (size_t)k * CAP;
    const float4* __restrict__ c4 = (const float4*)(ws + CAT);
    float* __restrict__ accV = ws + ACV;

    for (int p = blockIdx.y * 16 + slot; p < cnt; p += gridDim.y * 16) {
        int2 pr = pairs[p];
        const float4* cr = c4 + (size_t)pr.y * 8;
        float aV = 0.f;
        #pragma unroll
        for (int t = 0; t < 8; ++t) {
            float4 f = cr[t];
            aV += f.x * Wv_r[4*t] + f.y * Wv_r[4*t+1] + f.z * Wv_r[4*t+2] + f.w * Wv_r[4*t+3];
        }
        atomicAdd(&accV[(size_t)pr.x * 16 + o], aV);
    }
}

// vis center + BN + ReLU + sigmoid gate + blend -> out
__global__ __launch_bounds__(256) void finalizeB(
    const float* __restrict__ Wvis, float* __restrict__ ws,
    const float* __restrict__ gv, const float* __restrict__ bv,
    const float* __restrict__ mv, const float* __restrict__ vv,
    const float* __restrict__ w2, float* __restrict__ out)
{
    int o = threadIdx.x & 15;
    int slot = threadIdx.x >> 4;
    float Wv_r[32];
    #pragma unroll
    for (int c = 0; c < 32; ++c) Wv_r[c] = Wvis[CENTER_K * 512 + c * 16 + o];
    float sV = gv[o] * rsqrtf(vv[o] + EPSF), bV = bv[o], mV = mv[o], w2_ = w2[o];

    const float4* __restrict__ c4 = (const float4*)(ws + CAT);
    const float* __restrict__ cat = ws + CAT;
    const float* __restrict__ accV = ws + ACV;

    for (int n = blockIdx.x * 16 + slot; n < N_VOX; n += gridDim.x * 16) {
        const float4* cr = c4 + (size_t)n * 8;
        float aV = 0.f;
        #pragma unroll
        for (int t = 0; t < 8; ++t) {
            float4 f = cr[t];
            aV += f.x * Wv_r[4*t] + f.y * Wv_r[4*t+1] + f.z * Wv_r[4*t+2] + f.w * Wv_r[4*t+3];
        }
        float tV = accV[(size_t)n * 16 + o] + aV;
        float h = fmaxf((tV - mV) * sV + bV, 0.f);
        float ph = h * w2_;
        ph += __shfl_xor(ph, 1); ph += __shfl_xor(ph, 2);
        ph += __shfl_xor(ph, 4); ph += __shfl_xor(ph, 8);
        float vis = 1.f / (1.f + expf(-ph));
        float xi = cat[(size_t)n * 32 + o];
        float xp = cat[(size_t)n * 32 + 16 + o];
        out[(size_t)n * 16 + o] = vis * xi + (1.f - vis) * xp;
    }
}

extern "C" void kernel_launch(void* const* d_in, const int* in_sizes, int n_in,
                              void* d_out, int out_size, void* d_ws, size_t ws_size,
                              hipStream_t stream) {
    const float* fimg = (const float*)d_in[0];
    const float* fpts = (const float*)d_in[1];
    const int*   nbr  = (const int*)d_in[2];
    const float* Wimg = (const float*)d_in[3];
    const float* gi = (const float*)d_in[4];
    const float* bi = (const float*)d_in[5];
    const float* mi = (const float*)d_in[6];
    const float* vi = (const float*)d_in[7];
    const float* Wpts = (const float*)d_in[8];
    const float* gp = (const float*)d_in[9];
    const float* bp = (const float*)d_in[10];
    const float* mp = (const float*)d_in[11];
    const float* vp = (const float*)d_in[12];
    const float* Wvis = (const float*)d_in[13];
    const float* gv = (const float*)d_in[14];
    const float* bv = (const float*)d_in[15];
    const float* mv = (const float*)d_in[16];
    const float* vv = (const float*)d_in[17];
    const float* w2 = (const float*)d_in[18];
    float* out = (float*)d_out;
    float* ws = (float*)d_ws;

    hipLaunchKernelGGL(prep, dim3(1024), dim3(256), 0, stream, ws);
    hipLaunchKernelGGL(build_pairs, dim3(3072), dim3(256), 0, stream, nbr, ws);
    hipLaunchKernelGGL(scatterA, dim3(125, 16), dim3(256), 0, stream,
                       fimg, fpts, Wimg, Wpts, ws);
    hipLaunchKernelGGL(finalizeA, dim3(1024), dim3(256), 0, stream,
                       fimg, fpts, Wimg, Wpts, ws, gi, bi, mi, vi, gp, bp, mp, vp);
    hipLaunchKernelGGL(scatterV, dim3(125, 16), dim3(256), 0, stream, Wvis, ws);
    hipLaunchKernelGGL(finalizeB, dim3(1024), dim3(256), 0, stream,
                       Wvis, ws, gv, bv, mv, vv, w2, out);
}